// Round 22
// baseline (490.875 us; speedup 1.0000x reference)
//
#include <hip/hip_runtime.h>
#include <float.h>
#include <math.h>

#define VOCAB 128000
#define DIM   2048
#define SEQL  8
#define NB    32
#define SCAP  4096   // LDS candidate slots per row (expected ~100-250 used)

// ---------- helpers ----------
__device__ __forceinline__ unsigned f2sortable(float x){
  unsigned u = __float_as_uint(x);
  return (u & 0x80000000u) ? ~u : (u | 0x80000000u);  // monotone: bigger float -> bigger uint
}
__device__ __forceinline__ unsigned rotl32(unsigned x, int d){
  return (x << d) | (x >> (32 - d));
}

// JAX threefry gumbel, PARTITIONABLE path (verified passing r6/r8-r21): counter-mode,
// cipher input (0, n), key (0,42), output = XOR fold of the two output words.
__device__ float jax_gumbel(unsigned n){
  unsigned x0 = 0u, x1 = n;
  const unsigned k0 = 0u, k1 = 42u;
  const unsigned k2 = 0x1BD11BDAu ^ k0 ^ k1;
  x0 += k0; x1 += k1;
#define TFR(r) { x0 += x1; x1 = rotl32(x1, r); x1 ^= x0; }
  TFR(13) TFR(15) TFR(26) TFR(6)
  x0 += k1; x1 += k2 + 1u;
  TFR(17) TFR(29) TFR(16) TFR(24)
  x0 += k2; x1 += k0 + 2u;
  TFR(13) TFR(15) TFR(26) TFR(6)
  x0 += k0; x1 += k1 + 3u;
  TFR(17) TFR(29) TFR(16) TFR(24)
  x0 += k1; x1 += k2 + 4u;
  TFR(13) TFR(15) TFR(26) TFR(6)
  x0 += k2; x1 += k0 + 5u;
#undef TFR
  unsigned bits = x0 ^ x1;
  float f = __uint_as_float((bits >> 9) | 0x3f800000u) - 1.0f; // [0,1)
  float u = f + 1.17549435e-38f;
  return -logf(-logf(u));
}

// ---------- K1: logits = softcap(hs . E^T)/temp  (+ histogram fused in epilogue) ----------
// K-LOOP IS r12/r18 VERBATIM (421.5 us; only proven no-spill schedule). The ONLY
// change is epilogue-appended histogram atomics (4 scattered global atomicAdds per
// thread into hist_g[b][bin]) — integer adds, order-independent exact. This lets
// K2 drop one full 16 MB row pass.
__global__ __launch_bounds__(256, 4) void k_logits(
    const float* __restrict__ E, const float* __restrict__ HS,
    const float* __restrict__ temps, const int* __restrict__ posp,
    float* __restrict__ C, unsigned* __restrict__ hist_g)
{
  __shared__ float hs_s[2][NB * 64];
  __shared__ float tile[NB * 32];
  const int tid  = threadIdx.x;
  const int w    = tid >> 6;
  const int lane = tid & 63;
  const int g    = lane >> 4;
  const int qi   = lane & 15;
  const int pos  = posp[0];
  const int vbase = blockIdx.x * 32;
  const int vw    = vbase + w * 8;
  const int bofs  = blockIdx.x & 31;

  float acc[8][8];
#pragma unroll
  for (int j = 0; j < 8; ++j)
#pragma unroll
    for (int bl = 0; bl < 8; ++bl) acc[j][bl] = 0.f;

  const int sb0 = w * 8 + g;
  const int sb1 = w * 8 + 4 + g;
  const float* hsp0 = HS + ((size_t)(sb0 * SEQL + pos)) * DIM + qi * 4;
  const float* hsp1 = HS + ((size_t)(sb1 * SEQL + pos)) * DIM + qi * 4;
  const int lo0 = sb0 * 64 + qi * 4;
  const int lo1 = sb1 * 64 + qi * 4;

  { // prologue: rotated slice 0 -> buf 0
    float4 a = *(const float4*)(hsp0 + bofs * 64);
    float4 c = *(const float4*)(hsp1 + bofs * 64);
    *(float4*)&hs_s[0][lo0] = a;
    *(float4*)&hs_s[0][lo1] = c;
  }

  const float* Eb = E + (size_t)vw * DIM + qi * 4;

  for (int si = 0; si < 32; ++si){
    const int s = (si + bofs) & 31;
    __syncthreads();                       // slice s staged & visible for all waves
    float4 e[8];
#pragma unroll
    for (int j = 0; j < 8; ++j)
      e[j] = *(const float4*)(Eb + (size_t)j * DIM + s * 64);
    float4 n0, n1;
    const bool more = (si + 1 < 32);
    const int sn = (si + 1 + bofs) & 31;
    if (more){                             // issue next-slice stage loads early
      n0 = *(const float4*)(hsp0 + sn * 64);
      n1 = *(const float4*)(hsp1 + sn * 64);
    }
    const float* hb = &hs_s[si & 1][0];
#pragma unroll
    for (int bl = 0; bl < 8; ++bl){
      float4 h = *(const float4*)(hb + (g * 8 + bl) * 64 + qi * 4);
#pragma unroll
      for (int j = 0; j < 8; ++j){
        acc[j][bl] = fmaf(e[j].x, h.x, acc[j][bl]);
        acc[j][bl] = fmaf(e[j].y, h.y, acc[j][bl]);
        acc[j][bl] = fmaf(e[j].z, h.z, acc[j][bl]);
        acc[j][bl] = fmaf(e[j].w, h.w, acc[j][bl]);
      }
    }
    if (more){                             // write-late: protected by next iteration's barrier
      float* wb = &hs_s[(si + 1) & 1][0];
      *(float4*)&wb[lo0] = n0;
      *(float4*)&wb[lo1] = n1;
    }
  }

  // butterfly-reduce partials across the 16 qi-lanes of each b-quarter group
#pragma unroll
  for (int j = 0; j < 8; ++j)
#pragma unroll
    for (int bl = 0; bl < 8; ++bl){
      float v = acc[j][bl];
      v += __shfl_xor(v, 1, 64);
      v += __shfl_xor(v, 2, 64);
      v += __shfl_xor(v, 4, 64);
      v += __shfl_xor(v, 8, 64);
      acc[j][bl] = v;
    }
  if (qi == 0){
#pragma unroll
    for (int j = 0; j < 8; ++j)
#pragma unroll
      for (int bl = 0; bl < 8; ++bl)
        tile[(g * 8 + bl) * 32 + w * 8 + j] = acc[j][bl];
  }
  __syncthreads();
  { // coalesced epilogue: softcap + temperature, float4 stores, + hist atomics
    const int b = tid >> 3, vq = tid & 7;
    const float tmp = temps[b];
    float4 tv = *(const float4*)&tile[b * 32 + vq * 4];
    float4 o;
    o.x = (tanhf(tv.x / 30.f) * 30.f) / tmp;
    o.y = (tanhf(tv.y / 30.f) * 30.f) / tmp;
    o.z = (tanhf(tv.z / 30.f) * 30.f) / tmp;
    o.w = (tanhf(tv.w / 30.f) * 30.f) / tmp;
    *(float4*)(C + (size_t)b * VOCAB + vbase + vq * 4) = o;
    unsigned* hb_ = hist_g + b * 4096;
    atomicAdd(&hb_[f2sortable(o.x) >> 20], 1u);
    atomicAdd(&hb_[f2sortable(o.y) >> 20], 1u);
    atomicAdd(&hb_[f2sortable(o.z) >> 20], 1u);
    atomicAdd(&hb_[f2sortable(o.w) >> 20], 1u);
  }
}

// ---------- K2 (fused, ONE row pass): thresh from hist -> online (m,z) + collect ->
// deterministic merge -> probs -> exact top-64 -> top-k/top-p -> gumbel sample ----------
__global__ __launch_bounds__(1024) void k_sample_fused(
    const float* __restrict__ C,
    const float* __restrict__ tps, const int* __restrict__ tks,
    const unsigned* __restrict__ hist_g, float* __restrict__ out_tok)
{
  const int b = blockIdx.x, t = threadIdx.x;
  const float* row = C + (size_t)b * VOCAB;
  __shared__ unsigned hl[4096];
  __shared__ unsigned ps[1024];
  __shared__ float redm[1024];
  __shared__ float reds[1024];
  __shared__ float    cval_s[SCAP];
  __shared__ int      cidx_s[SCAP];
  __shared__ int tbin_s;
  __shared__ unsigned cnt_s;

  if (t == 0) cnt_s = 0u;
  for (int i = t; i < 4096; i += 1024) hl[i] = hist_g[b * 4096 + i];
  __syncthreads();

  // suffix scan over 1024 thread-partials (4 bins each) -> bin containing 64th-largest
  unsigned s_t = 0u;
#pragma unroll
  for (int k = 0; k < 4; ++k) s_t += hl[t * 4 + k];
  ps[t] = s_t; __syncthreads();
  for (int off = 1; off < 1024; off <<= 1){
    unsigned v = ps[t] + ((t + off < 1024) ? ps[t + off] : 0u);
    __syncthreads();
    ps[t] = v;
    __syncthreads();
  }
  const unsigned Sstrict = ps[t] - s_t;       // count in threads > t
  if (Sstrict < 64u && ps[t] >= 64u){
    unsigned c = Sstrict;
    for (int bb = 3; bb >= 0; --bb){
      c += hl[t * 4 + bb];
      if (c >= 64u){ tbin_s = t * 4 + bb; break; }
    }
  }
  __syncthreads();
  const unsigned thr = ((unsigned)tbin_s) << 20;

  // SINGLE row pass: online max+sumexp AND candidate collect
  float m_run = -FLT_MAX, zs = 0.f;
  for (int f = t; f < VOCAB / 4; f += 1024){
    float4 x4 = ((const float4*)row)[f];
    float xs[4] = {x4.x, x4.y, x4.z, x4.w};
    float mx = fmaxf(fmaxf(xs[0], xs[1]), fmaxf(xs[2], xs[3]));
    float nm = fmaxf(m_run, mx);
    zs = zs * expf(m_run - nm);       // first iter: 0 * exp(-inf) = 0
#pragma unroll
    for (int c = 0; c < 4; ++c){
      zs += expf(xs[c] - nm);
      if (f2sortable(xs[c]) >= thr){
        unsigned slot = atomicAdd(&cnt_s, 1u);
        if (slot < (unsigned)SCAP){
          cval_s[slot] = xs[c];
          cidx_s[slot] = f * 4 + c;
        }
      }
    }
    m_run = nm;
  }
  redm[t] = m_run; reds[t] = zs; __syncthreads();
  for (int sft = 512; sft > 0; sft >>= 1){
    if (t < sft){
      float m1 = redm[t], s1 = reds[t];
      float m2 = redm[t + sft], s2 = reds[t + sft];
      float nm = fmaxf(m1, m2);
      redm[t] = nm;
      reds[t] = s1 * expf(m1 - nm) + s2 * expf(m2 - nm);
    }
    __syncthreads();
  }
  const float m = redm[0], Z = reds[0];
  int cn = (int)cnt_s; if (cn > SCAP) cn = SCAP;

  // transform candidates to reference probs in place
  for (int j = t; j < cn; j += 1024)
    cval_s[j] = expf(cval_s[j] - m) / Z;
  __syncthreads();

  // wave 0 only: exact 64-rank predicate-walk by (p desc, idx asc), then mask+sample
  if (t < 64){
    float my_sp = 0.f; int my_si = 0;
    float lp = FLT_MAX; int li = -1;
    for (int r = 0; r < 64; ++r){
      float bp = -1.f; int bi = 0x7fffffff;
      for (int j = t; j < cn; j += 64){
        float p = cval_s[j]; int id = cidx_s[j];
        bool valid = (p < lp) || (p == lp && id > li);
        if (valid && (p > bp || (p == bp && id < bi))){ bp = p; bi = id; }
      }
#pragma unroll
      for (int off = 32; off >= 1; off >>= 1){
        float op = __shfl_xor(bp, off, 64);
        int   oi = __shfl_xor(bi, off, 64);
        if (op > bp || (op == bp && oi < bi)){ bp = op; bi = oi; }
      }
      if (t == r){ my_sp = bp; my_si = bi; }
      lp = bp; li = bi;
    }

    const float tp = tps[b];
    const int   tk = tks[b];
    float c = 0.f, sren = 0.f;
    bool keep_me = false;
    for (int j = 0; j < 64; ++j){
      float pj = __shfl(my_sp, j, 64);
      c = c + pj;
      float excl = c - pj;                      // cum - probs_sort
      bool keep = (!(excl > tp)) && (j < tk);
      if (j == t) keep_me = keep;
      if (keep) sren = sren + pj;
    }

    float score = -FLT_MAX;
    int vid = my_si;
    if (keep_me){
      float pf = my_sp / sren;
      score = logf(pf) + jax_gumbel((unsigned)(b * VOCAB + vid));
    }
    float bs = score; int bv = vid;
#pragma unroll
    for (int off = 32; off >= 1; off >>= 1){
      float os = __shfl_xor(bs, off, 64);
      int   ov = __shfl_xor(bv, off, 64);
      if (os > bs || (os == bs && ov < bv)){ bs = os; bv = ov; }
    }
    if (t == 0) out_tok[b] = (float)bv;
  }
}

extern "C" void kernel_launch(void* const* d_in, const int* in_sizes, int n_in,
                              void* d_out, int out_size, void* d_ws, size_t ws_size,
                              hipStream_t stream)
{
  (void)in_sizes; (void)n_in; (void)out_size; (void)ws_size;
  const float* emb   = (const float*)d_in[0];
  const float* hs    = (const float*)d_in[1];
  const float* temps = (const float*)d_in[2];
  const float* tps   = (const float*)d_in[3];
  const int*   posp  = (const int*)d_in[4];
  const int*   tks   = (const int*)d_in[5];
  float* out = (float*)d_out;
  float* C   = out + NB;                    // logits [32][128000]; tokens in out[0..31]

  unsigned* hist_g = (unsigned*)d_ws;       // 32 x 4096 bins = 512 KB
  hipMemsetAsync(hist_g, 0, (size_t)NB * 4096 * sizeof(unsigned), stream);

  k_logits      <<<dim3(VOCAB / 32), dim3(256),  0, stream>>>(emb, hs, temps, posp, C, hist_g);
  k_sample_fused<<<dim3(NB),         dim3(1024), 0, stream>>>(C, tps, tks, hist_g, out);
}

// Round 23
// 420.477 us; speedup vs baseline: 1.1674x; 1.1674x over previous
//
#include <hip/hip_runtime.h>
#include <float.h>
#include <math.h>

#define VOCAB 128000
#define DIM   2048
#define SEQL  8
#define NB    32
#define SCAP  4096   // LDS candidate slots per row (expected ~100-250 used)

// ---------- helpers ----------
__device__ __forceinline__ unsigned f2sortable(float x){
  unsigned u = __float_as_uint(x);
  return (u & 0x80000000u) ? ~u : (u | 0x80000000u);  // monotone: bigger float -> bigger uint
}
__device__ __forceinline__ unsigned rotl32(unsigned x, int d){
  return (x << d) | (x >> (32 - d));
}

// JAX threefry gumbel, PARTITIONABLE path (verified passing r6/r8-r22): counter-mode,
// cipher input (0, n), key (0,42), output = XOR fold of the two output words.
__device__ float jax_gumbel(unsigned n){
  unsigned x0 = 0u, x1 = n;
  const unsigned k0 = 0u, k1 = 42u;
  const unsigned k2 = 0x1BD11BDAu ^ k0 ^ k1;
  x0 += k0; x1 += k1;
#define TFR(r) { x0 += x1; x1 = rotl32(x1, r); x1 ^= x0; }
  TFR(13) TFR(15) TFR(26) TFR(6)
  x0 += k1; x1 += k2 + 1u;
  TFR(17) TFR(29) TFR(16) TFR(24)
  x0 += k2; x1 += k0 + 2u;
  TFR(13) TFR(15) TFR(26) TFR(6)
  x0 += k0; x1 += k1 + 3u;
  TFR(17) TFR(29) TFR(16) TFR(24)
  x0 += k1; x1 += k2 + 4u;
  TFR(13) TFR(15) TFR(26) TFR(6)
  x0 += k2; x1 += k0 + 5u;
#undef TFR
  unsigned bits = x0 ^ x1;
  float f = __uint_as_float((bits >> 9) | 0x3f800000u) - 1.0f; // [0,1)
  float u = f + 1.17549435e-38f;
  return -logf(-logf(u));
}

// ---------- K1: logits = softcap(hs . E^T)/temp ----------
// r12/r18 VERBATIM — empirical optimum (421.5 us). The only proven no-spill
// register schedule (e[8]=32 + n0/n1=8 + acc=64 under the (256,4) 128-VGPR cap).
// 12 structural alternatives regressed or spilled (r8-r22 evidence table).
__global__ __launch_bounds__(256, 4) void k_logits(
    const float* __restrict__ E, const float* __restrict__ HS,
    const float* __restrict__ temps, const int* __restrict__ posp,
    float* __restrict__ C)
{
  __shared__ float hs_s[2][NB * 64];
  __shared__ float tile[NB * 32];
  const int tid  = threadIdx.x;
  const int w    = tid >> 6;
  const int lane = tid & 63;
  const int g    = lane >> 4;
  const int qi   = lane & 15;
  const int pos  = posp[0];
  const int vbase = blockIdx.x * 32;
  const int vw    = vbase + w * 8;
  const int bofs  = blockIdx.x & 31;     // slice rotation

  float acc[8][8];
#pragma unroll
  for (int j = 0; j < 8; ++j)
#pragma unroll
    for (int bl = 0; bl < 8; ++bl) acc[j][bl] = 0.f;

  const int sb0 = w * 8 + g;
  const int sb1 = w * 8 + 4 + g;
  const float* hsp0 = HS + ((size_t)(sb0 * SEQL + pos)) * DIM + qi * 4;
  const float* hsp1 = HS + ((size_t)(sb1 * SEQL + pos)) * DIM + qi * 4;
  const int lo0 = sb0 * 64 + qi * 4;
  const int lo1 = sb1 * 64 + qi * 4;

  { // prologue: rotated slice 0 -> buf 0
    float4 a = *(const float4*)(hsp0 + bofs * 64);
    float4 c = *(const float4*)(hsp1 + bofs * 64);
    *(float4*)&hs_s[0][lo0] = a;
    *(float4*)&hs_s[0][lo1] = c;
  }

  const float* Eb = E + (size_t)vw * DIM + qi * 4;

  for (int si = 0; si < 32; ++si){
    const int s = (si + bofs) & 31;
    __syncthreads();                       // slice s staged & visible for all waves
    float4 e[8];
#pragma unroll
    for (int j = 0; j < 8; ++j)
      e[j] = *(const float4*)(Eb + (size_t)j * DIM + s * 64);
    float4 n0, n1;
    const bool more = (si + 1 < 32);
    const int sn = (si + 1 + bofs) & 31;
    if (more){                             // issue next-slice stage loads early
      n0 = *(const float4*)(hsp0 + sn * 64);
      n1 = *(const float4*)(hsp1 + sn * 64);
    }
    const float* hb = &hs_s[si & 1][0];
#pragma unroll
    for (int bl = 0; bl < 8; ++bl){
      float4 h = *(const float4*)(hb + (g * 8 + bl) * 64 + qi * 4);
#pragma unroll
      for (int j = 0; j < 8; ++j){
        acc[j][bl] = fmaf(e[j].x, h.x, acc[j][bl]);
        acc[j][bl] = fmaf(e[j].y, h.y, acc[j][bl]);
        acc[j][bl] = fmaf(e[j].z, h.z, acc[j][bl]);
        acc[j][bl] = fmaf(e[j].w, h.w, acc[j][bl]);
      }
    }
    if (more){                             // write-late: protected by next iteration's barrier
      float* wb = &hs_s[(si + 1) & 1][0];
      *(float4*)&wb[lo0] = n0;
      *(float4*)&wb[lo1] = n1;
    }
  }

  // butterfly-reduce partials across the 16 qi-lanes of each b-quarter group
#pragma unroll
  for (int j = 0; j < 8; ++j)
#pragma unroll
    for (int bl = 0; bl < 8; ++bl){
      float v = acc[j][bl];
      v += __shfl_xor(v, 1, 64);
      v += __shfl_xor(v, 2, 64);
      v += __shfl_xor(v, 4, 64);
      v += __shfl_xor(v, 8, 64);
      acc[j][bl] = v;
    }
  if (qi == 0){
#pragma unroll
    for (int j = 0; j < 8; ++j)
#pragma unroll
      for (int bl = 0; bl < 8; ++bl)
        tile[(g * 8 + bl) * 32 + w * 8 + j] = acc[j][bl];
  }
  __syncthreads();
  { // coalesced epilogue: softcap + temperature, float4 stores
    const int b = tid >> 3, vq = tid & 7;
    const float tmp = temps[b];
    float4 tv = *(const float4*)&tile[b * 32 + vq * 4];
    float4 o;
    o.x = (tanhf(tv.x / 30.f) * 30.f) / tmp;
    o.y = (tanhf(tv.y / 30.f) * 30.f) / tmp;
    o.z = (tanhf(tv.z / 30.f) * 30.f) / tmp;
    o.w = (tanhf(tv.w / 30.f) * 30.f) / tmp;
    *(float4*)(C + (size_t)b * VOCAB + vbase + vq * 4) = o;
  }
}

// ---------- K2 (fused): online (max,sumexp)+hist in ONE pass, collect, top-64, sample ----
// One block (1024 thr) per row. 2 passes over the row (validated r16-r18, r20-r21).
__global__ __launch_bounds__(1024) void k_sample_fused(
    const float* __restrict__ C,
    const float* __restrict__ tps, const int* __restrict__ tks,
    float* __restrict__ out_tok)
{
  const int b = blockIdx.x, t = threadIdx.x;
  const float* row = C + (size_t)b * VOCAB;
  __shared__ float redm[1024];
  __shared__ float reds[1024];
  __shared__ unsigned ps[1024];
  __shared__ unsigned hist[4096];     // 12-bit sortable prefix
  __shared__ float    cval_s[SCAP];
  __shared__ int      cidx_s[SCAP];
  __shared__ int tbin_s;
  __shared__ unsigned cnt_s;

  if (t == 0) cnt_s = 0u;
  for (int i = t; i < 4096; i += 1024) hist[i] = 0u;
  __syncthreads();

  // pass A: online max+sumexp + histogram (single read of the row)
  float m_run = -FLT_MAX, zs = 0.f;
  for (int f = t; f < VOCAB / 4; f += 1024){
    float4 x4 = ((const float4*)row)[f];
    float xs[4] = {x4.x, x4.y, x4.z, x4.w};
    float mx = fmaxf(fmaxf(xs[0], xs[1]), fmaxf(xs[2], xs[3]));
    float nm = fmaxf(m_run, mx);
    zs = zs * expf(m_run - nm);       // first iter: 0 * exp(-inf) = 0
#pragma unroll
    for (int c = 0; c < 4; ++c){
      zs += expf(xs[c] - nm);
      atomicAdd(&hist[f2sortable(xs[c]) >> 20], 1u);
    }
    m_run = nm;
  }
  redm[t] = m_run; reds[t] = zs; __syncthreads();
  for (int sft = 512; sft > 0; sft >>= 1){
    if (t < sft){
      float m1 = redm[t], s1 = reds[t];
      float m2 = redm[t + sft], s2 = reds[t + sft];
      float nm = fmaxf(m1, m2);
      redm[t] = nm;
      reds[t] = s1 * expf(m1 - nm) + s2 * expf(m2 - nm);
    }
    __syncthreads();
  }
  const float m = redm[0], Z = reds[0];

  // suffix scan over 1024 thread-partials (4 bins each) -> bin containing 64th-largest
  unsigned s_t = 0u;
#pragma unroll
  for (int k = 0; k < 4; ++k) s_t += hist[t * 4 + k];
  ps[t] = s_t; __syncthreads();
  for (int off = 1; off < 1024; off <<= 1){
    unsigned v = ps[t] + ((t + off < 1024) ? ps[t + off] : 0u);
    __syncthreads();
    ps[t] = v;
    __syncthreads();
  }
  const unsigned Sstrict = ps[t] - s_t;       // count in threads > t
  if (Sstrict < 64u && ps[t] >= 64u){
    unsigned c = Sstrict;
    for (int bb = 3; bb >= 0; --bb){
      c += hist[t * 4 + bb];
      if (c >= 64u){ tbin_s = t * 4 + bb; break; }
    }
  }
  __syncthreads();
  const unsigned thr = ((unsigned)tbin_s) << 20;

  // pass B: collect candidates (exact superset of top-64 by construction)
  for (int f = t; f < VOCAB / 4; f += 1024){
    float4 x4 = ((const float4*)row)[f];
    float xs[4] = {x4.x, x4.y, x4.z, x4.w};
#pragma unroll
    for (int c = 0; c < 4; ++c){
      if (f2sortable(xs[c]) >= thr){
        unsigned slot = atomicAdd(&cnt_s, 1u);
        if (slot < (unsigned)SCAP){
          cval_s[slot] = xs[c];
          cidx_s[slot] = f * 4 + c;
        }
      }
    }
  }
  __syncthreads();
  int cn = (int)cnt_s; if (cn > SCAP) cn = SCAP;

  // transform candidates to reference probs in place
  for (int j = t; j < cn; j += 1024)
    cval_s[j] = expf(cval_s[j] - m) / Z;
  __syncthreads();

  // wave 0 only: exact 64-rank predicate-walk by (p desc, idx asc), then mask+sample
  if (t < 64){
    float my_sp = 0.f; int my_si = 0;
    float lp = FLT_MAX; int li = -1;
    for (int r = 0; r < 64; ++r){
      float bp = -1.f; int bi = 0x7fffffff;
      for (int j = t; j < cn; j += 64){
        float p = cval_s[j]; int id = cidx_s[j];
        bool valid = (p < lp) || (p == lp && id > li);
        if (valid && (p > bp || (p == bp && id < bi))){ bp = p; bi = id; }
      }
#pragma unroll
      for (int off = 32; off >= 1; off >>= 1){
        float op = __shfl_xor(bp, off, 64);
        int   oi = __shfl_xor(bi, off, 64);
        if (op > bp || (op == bp && oi < bi)){ bp = op; bi = oi; }
      }
      if (t == r){ my_sp = bp; my_si = bi; }
      lp = bp; li = bi;
    }

    const float tp = tps[b];
    const int   tk = tks[b];
    float c = 0.f, sren = 0.f;
    bool keep_me = false;
    for (int j = 0; j < 64; ++j){
      float pj = __shfl(my_sp, j, 64);
      c = c + pj;
      float excl = c - pj;                      // cum - probs_sort
      bool keep = (!(excl > tp)) && (j < tk);
      if (j == t) keep_me = keep;
      if (keep) sren = sren + pj;
    }

    float score = -FLT_MAX;
    int vid = my_si;
    if (keep_me){
      float pf = my_sp / sren;
      score = logf(pf) + jax_gumbel((unsigned)(b * VOCAB + vid));
    }
    float bs = score; int bv = vid;
#pragma unroll
    for (int off = 32; off >= 1; off >>= 1){
      float os = __shfl_xor(bs, off, 64);
      int   ov = __shfl_xor(bv, off, 64);
      if (os > bs || (os == bs && ov < bv)){ bs = os; bv = ov; }
    }
    if (t == 0) out_tok[b] = (float)bv;
  }
}

extern "C" void kernel_launch(void* const* d_in, const int* in_sizes, int n_in,
                              void* d_out, int out_size, void* d_ws, size_t ws_size,
                              hipStream_t stream)
{
  (void)in_sizes; (void)n_in; (void)out_size; (void)d_ws; (void)ws_size;
  const float* emb   = (const float*)d_in[0];
  const float* hs    = (const float*)d_in[1];
  const float* temps = (const float*)d_in[2];
  const float* tps   = (const float*)d_in[3];
  const int*   posp  = (const int*)d_in[4];
  const int*   tks   = (const int*)d_in[5];
  float* out = (float*)d_out;
  float* C   = out + NB;                    // logits [32][128000]; tokens in out[0..31]

  k_logits      <<<dim3(VOCAB / 32), dim3(256),  0, stream>>>(emb, hs, temps, posp, C);
  k_sample_fused<<<dim3(NB),         dim3(1024), 0, stream>>>(C, tps, tks, out);
}